// Round 7
// baseline (1520.086 us; speedup 1.0000x reference)
//
#include <hip/hip_runtime.h>

typedef __attribute__((ext_vector_type(8))) short bf16x8;
typedef __attribute__((ext_vector_type(4))) float f32x4;

#define BDIM 32768
#define DDIM 2048
#define HNUM 16
#define HD   128

// ---------- helpers ----------
__device__ inline short f2bf(float f) {
    union { float f; unsigned u; } v; v.f = f;
    unsigned r = v.u + 0x7FFFu + ((v.u >> 16) & 1u);   // round-to-nearest-even
    return (short)(r >> 16);
}
__device__ inline float bf2f(short s) {
    union { unsigned u; float f; } v; v.u = ((unsigned)(unsigned short)s) << 16; return v.f;
}

__device__ inline void load_lds16(const void* g, void* l) {
    __builtin_amdgcn_global_load_lds(
        (const __attribute__((address_space(1))) void*)g,
        (__attribute__((address_space(3))) void*)l, 16, 0, 0);
}

#define VMCNT(n) asm volatile("s_waitcnt vmcnt(" #n ")" ::: "memory")
#define LGKM8    asm volatile("s_waitcnt lgkmcnt(8)" ::: "memory")
#define LGKM0    do { asm volatile("s_waitcnt lgkmcnt(0)" ::: "memory"); __builtin_amdgcn_sched_barrier(0); } while (0)
#define BARX     do { __builtin_amdgcn_s_barrier(); __builtin_amdgcn_sched_barrier(0); } while (0)
#define SP1      __builtin_amdgcn_s_setprio(1)
#define SP0      __builtin_amdgcn_s_setprio(0)

// ---------- fp32 -> bf16 convert ----------
__global__ __launch_bounds__(256)
void cvt1(const float* __restrict__ in, short* __restrict__ out, int n8)
{
    int idx = blockIdx.x * 256 + threadIdx.x;
    int stride = gridDim.x * 256;
    for (int ch = idx; ch < n8; ch += stride) {
        const float4* p = (const float4*)(in + (size_t)ch * 8);
        float4 x0 = p[0], x1 = p[1];
        union { bf16x8 v; short s[8]; } o;
        o.s[0] = f2bf(x0.x); o.s[1] = f2bf(x0.y); o.s[2] = f2bf(x0.z); o.s[3] = f2bf(x0.w);
        o.s[4] = f2bf(x1.x); o.s[5] = f2bf(x1.y); o.s[6] = f2bf(x1.z); o.s[7] = f2bf(x1.w);
        *(bf16x8*)(out + (size_t)ch * 8) = o.v;
    }
}

// ---------- weight transpose + convert: W[K][N] fp32 -> Wt[N][K] bf16 ----------
__global__ __launch_bounds__(256)
void wtrans(const float* __restrict__ w0, const float* __restrict__ w1,
            const float* __restrict__ w2, const float* __restrict__ w3,
            short* __restrict__ o0, short* __restrict__ o1,
            short* __restrict__ o2, short* __restrict__ o3)
{
    const float* W = blockIdx.z == 0 ? w0 : blockIdx.z == 1 ? w1 : blockIdx.z == 2 ? w2 : w3;
    short*       O = blockIdx.z == 0 ? o0 : blockIdx.z == 1 ? o1 : blockIdx.z == 2 ? o2 : o3;
    __shared__ float t[32][33];
    int bx = blockIdx.x * 32;   // n
    int by = blockIdx.y * 32;   // k
    int tx = threadIdx.x, ty = threadIdx.y;  // 32 x 8
    #pragma unroll
    for (int r = 0; r < 4; ++r)
        t[ty + 8*r][tx] = W[(size_t)(by + ty + 8*r) * DDIM + bx + tx];
    __syncthreads();
    #pragma unroll
    for (int r = 0; r < 4; ++r)
        O[(size_t)(bx + ty + 8*r) * DDIM + by + tx] = f2bf(t[tx][ty + 8*r]);
}

// ---------- 256x256 8-wave 8-phase bf16 GEMM (m201-faithful phases) ----------
// Phase = { ds_reads(this quad) ; stage(1 half-tile) ; [lgkmcnt(8)] ; BAR ;
//           lgkmcnt(0) ; SP1 16xMFMA SP0 ; [vmcnt(6) @ph3/ph7] ; BAR }
// MFMA operands SWAPPED: acc = mfma(b, a) holds C^T fragment -> lane owns
// row = lane&15, cols = lgrp*4 + reg (4 consecutive) -> 8B packed stores.

template<int MH, int NH>
__device__ inline void quadf(f32x4 (&acc)[8][4], bf16x8 (&a)[4][2], bf16x8 (&b)[2][2])
{
    #pragma unroll
    for (int kk = 0; kk < 2; ++kk)
        #pragma unroll
        for (int mi = 0; mi < 4; ++mi)
            #pragma unroll
            for (int ni = 0; ni < 2; ++ni)
                acc[MH*4 + mi][NH*2 + ni] = __builtin_amdgcn_mfma_f32_16x16x32_bf16(
                    b[ni][kk], a[mi][kk], acc[MH*4 + mi][NH*2 + ni], 0, 0, 0);
}

template<int MODE>
__global__ __launch_bounds__(512)
void gemm8(const short* __restrict__ A, const short* __restrict__ Bt,
           const float* __restrict__ bias, const short* __restrict__ resid,
           short* __restrict__ Cb, float* __restrict__ Cf)
{
    constexpr int K = 2048, N = 2048;
    constexpr int NT = K >> 6;            // 32 K-tiles
    constexpr int NP = (NT >> 1) - 1;     // 15 full iterations
    __shared__ __align__(16) short lds[2][2][256 * 64];
    const int tid = threadIdx.x;

    constexpr int cpx = 128;              // 1024 wgs / 8 XCDs
    const int wg  = ((int)blockIdx.x & 7) * cpx + ((int)blockIdx.x >> 3);
    const int tm  = wg >> 3, tn = wg & 7;

    const int wave = tid >> 6, lane = tid & 63;
    const int wm = wave >> 2, wn = wave & 3;        // 2 x 4 wave grid, 128x64 out each
    const int lrow = lane & 15, lgrp = lane >> 4;

    const short* Ab = A  + (size_t)tm * 256 * K;
    const short* Bb = Bt + (size_t)tn * 256 * K;

    // ---- staging streams: precomputed pointers + LDS offsets ----
    const int r0 = tid >> 3, c0 = tid & 7;
    const int cg = c0 ^ (r0 & 7);                   // inverse swizzle on source
    constexpr size_t DL  = (size_t)128 * K;         // second-load global delta
    constexpr int    DLD = 128 * 64;                // second-load LDS delta
    const int rB = ((r0 >> 5) << 6) | (r0 & 31);    // B row for B0 stream

    const short* pA0 = Ab + (size_t)r0 * K + cg * 8;
    const short* pA1 = Ab + (size_t)(64 + r0) * K + cg * 8;
    const short* pB0 = Bb + (size_t)rB * K + cg * 8;
    const short* pB1 = Bb + (size_t)(rB + 32) * K + cg * 8;

    short* base = &lds[0][0][0];
    int oA0 = r0 * 64 + c0 * 8;                     // into [buf][0]
    int oA1 = (64 + r0) * 64 + c0 * 8;
    int oB0 = 16384 + rB * 64 + c0 * 8;             // into [buf][1]
    int oB1 = 16384 + (rB + 32) * 64 + c0 * 8;

    auto stA0 = [&]{ load_lds16(pA0, base + oA0); load_lds16(pA0 + DL, base + oA0 + DLD); pA0 += 64; oA0 ^= 32768; };
    auto stA1 = [&]{ load_lds16(pA1, base + oA1); load_lds16(pA1 + DL, base + oA1 + DLD); pA1 += 64; oA1 ^= 32768; };
    auto stB0 = [&]{ load_lds16(pB0, base + oB0); load_lds16(pB0 + DL, base + oB0 + DLD); pB0 += 64; oB0 ^= 32768; };
    auto stB1 = [&]{ load_lds16(pB1, base + oB1); load_lds16(pB1 + DL, base + oB1 + DLD); pB1 += 64; oB1 ^= 32768; };

    // ---- fragment reads ----
    bf16x8 a[4][2], b0[2][2], b1[2][2];
    const int sw0 = (lgrp ^ (lrow & 7)) * 8;
    const int sw1 = ((4 + lgrp) ^ (lrow & 7)) * 8;

    auto readA = [&](int buf, int mh) {
        const short* s = &lds[buf][0][0];
        int bb = (wm * 128 + mh * 64 + lrow) * 64;
        #pragma unroll
        for (int mi = 0; mi < 4; ++mi) {
            a[mi][0] = *(const bf16x8*)&s[bb + mi * 1024 + sw0];
            a[mi][1] = *(const bf16x8*)&s[bb + mi * 1024 + sw1];
        }
    };
    auto readB = [&](int buf, int nh, bf16x8 (&b)[2][2]) {
        const short* s = &lds[buf][1][0];
        int bb = (wn * 64 + nh * 32 + lrow) * 64;
        #pragma unroll
        for (int ni = 0; ni < 2; ++ni) {
            b[ni][0] = *(const bf16x8*)&s[bb + ni * 1024 + sw0];
            b[ni][1] = *(const bf16x8*)&s[bb + ni * 1024 + sw1];
        }
    };

    f32x4 acc[8][4] = {};

    // prologue: tile0 -> buf0 (full), tile1 -> buf1 (A0,B0,B1); 14 loads in flight
    stA0(); stB0(); stB1(); stA1();
    stA0(); stB0(); stB1();
    VMCNT(6);                 // per-wave: own 8 tile0 loads landed
    BARX;                     // publish tile0 across waves

    for (int j = 0; j < NP; ++j) {
        // ph0: quad(0,0) on buf0
        readA(0, 0); readB(0, 0, b0);       // 12 ds_reads
        stA1();                              // A1(2j+1) -> buf1
        LGKM8;
        BARX; LGKM0;
        SP1; quadf<0,0>(acc, a, b0); SP0;
        BARX;
        // ph1: quad(0,1)
        readB(0, 1, b1);
        stA0();                              // A0(2j+2) -> buf0
        BARX; LGKM0;
        SP1; quadf<0,1>(acc, a, b1); SP0;
        BARX;
        // ph2: quad(1,0)
        readA(0, 1);
        stB0();                              // B0(2j+2) -> buf0
        BARX; LGKM0;
        SP1; quadf<1,0>(acc, a, b0); SP0;
        BARX;
        // ph3: quad(1,1), register-held; vmcnt(6) lands tile 2j+1
        stB1();                              // B1(2j+2) -> buf0
        BARX;
        SP1; quadf<1,1>(acc, a, b1); SP0;
        VMCNT(6);
        BARX;
        // ph4: quad(0,0) on buf1
        readA(1, 0); readB(1, 0, b0);
        stA1();                              // A1(2j+2) -> buf0
        LGKM8;
        BARX; LGKM0;
        SP1; quadf<0,0>(acc, a, b0); SP0;
        BARX;
        // ph5
        readB(1, 1, b1);
        stA0();                              // A0(2j+3) -> buf1
        BARX; LGKM0;
        SP1; quadf<0,1>(acc, a, b1); SP0;
        BARX;
        // ph6
        readA(1, 1);
        stB0();                              // B0(2j+3) -> buf1
        BARX; LGKM0;
        SP1; quadf<1,0>(acc, a, b0); SP0;
        BARX;
        // ph7: vmcnt(6) lands tile 2j+2
        stB1();                              // B1(2j+3) -> buf1
        BARX;
        SP1; quadf<1,1>(acc, a, b1); SP0;
        VMCNT(6);
        BARX;
    }

    // epilogue: buf0 = tile NT-2, buf1 = tile NT-1; in flight: A0,B0,B1(NT-1)
    // e0
    readA(0, 0); readB(0, 0, b0);
    stA1();                                  // A1(NT-1) -> buf1 (last stage)
    LGKM8;
    BARX; LGKM0;
    SP1; quadf<0,0>(acc, a, b0); SP0;
    BARX;
    // e1
    readB(0, 1, b1);
    BARX; LGKM0;
    SP1; quadf<0,1>(acc, a, b1); SP0;
    BARX;
    // e2
    readA(0, 1);
    BARX; LGKM0;
    SP1; quadf<1,0>(acc, a, b0); SP0;
    BARX;
    // e3: vmcnt(0) lands all of tile NT-1
    BARX;
    SP1; quadf<1,1>(acc, a, b1); SP0;
    VMCNT(0);
    BARX;
    // e4..e7: tile NT-1, no more LDS writes -> no barriers needed
    readA(1, 0); readB(1, 0, b0);
    quadf<0,0>(acc, a, b0);
    readB(1, 1, b1);
    quadf<0,1>(acc, a, b1);
    readA(1, 1);
    quadf<1,0>(acc, a, b0);
    quadf<1,1>(acc, a, b1);

    // ---- C write (C^T fragments): lane owns row=lrow, 4 consecutive cols ----
    #pragma unroll
    for (int m = 0; m < 8; ++m) {
        const int row = tm * 256 + wm * 128 + m * 16 + lrow;
        const size_t rb = (size_t)row * N;
        #pragma unroll
        for (int n = 0; n < 4; ++n) {
            const int col = tn * 256 + wn * 64 + n * 16 + lgrp * 4;
            f32x4 v = acc[m][n];
            float4 bv = *(const float4*)&bias[col];
            v[0] += bv.x; v[1] += bv.y; v[2] += bv.z; v[3] += bv.w;
            if (MODE == 0) {
                uint2 w;
                w.x = (unsigned)(unsigned short)f2bf(v[0]) | ((unsigned)(unsigned short)f2bf(v[1]) << 16);
                w.y = (unsigned)(unsigned short)f2bf(v[2]) | ((unsigned)(unsigned short)f2bf(v[3]) << 16);
                *(uint2*)(Cb + rb + col) = w;
            } else {
                uint2 rv = *(const uint2*)(resid + rb + col);
                v[0] += bf2f((short)(rv.x & 0xffff));
                v[1] += bf2f((short)(rv.x >> 16));
                v[2] += bf2f((short)(rv.y & 0xffff));
                v[3] += bf2f((short)(rv.y >> 16));
                *(f32x4*)(Cf + rb + col) = v;
            }
        }
    }
}

// ---------- per-sample 16-head cosine attention (bf16 in), transposed bf16 out ----------
#define PAD 132

__global__ __launch_bounds__(256)
void attn(const short* __restrict__ qp, const short* __restrict__ kp,
          const short* __restrict__ vp, short* __restrict__ ot)
{
    __shared__ __align__(16) float qs[HNUM * PAD];
    __shared__ __align__(16) float ks[HNUM * PAD];
    __shared__ __align__(16) float vs[HNUM * PAD];
    __shared__ float rq[HNUM], rk[HNUM], sm[HNUM * 17];

    const int b = blockIdx.x;
    const int tid = threadIdx.x;
    const short* qr = qp + (size_t)b * DDIM;
    const short* kr = kp + (size_t)b * DDIM;
    const short* vr = vp + (size_t)b * DDIM;

    {
        int e = tid * 8;
        int h = e >> 7, d = e & 127;
        union { bf16x8 v; short s[8]; } u;
        float4 f0, f1;
        u.v = *(const bf16x8*)(qr + e);
        f0.x = bf2f(u.s[0]); f0.y = bf2f(u.s[1]); f0.z = bf2f(u.s[2]); f0.w = bf2f(u.s[3]);
        f1.x = bf2f(u.s[4]); f1.y = bf2f(u.s[5]); f1.z = bf2f(u.s[6]); f1.w = bf2f(u.s[7]);
        *(float4*)&qs[h * PAD + d] = f0; *(float4*)&qs[h * PAD + d + 4] = f1;
        u.v = *(const bf16x8*)(kr + e);
        f0.x = bf2f(u.s[0]); f0.y = bf2f(u.s[1]); f0.z = bf2f(u.s[2]); f0.w = bf2f(u.s[3]);
        f1.x = bf2f(u.s[4]); f1.y = bf2f(u.s[5]); f1.z = bf2f(u.s[6]); f1.w = bf2f(u.s[7]);
        *(float4*)&ks[h * PAD + d] = f0; *(float4*)&ks[h * PAD + d + 4] = f1;
        u.v = *(const bf16x8*)(vr + e);
        f0.x = bf2f(u.s[0]); f0.y = bf2f(u.s[1]); f0.z = bf2f(u.s[2]); f0.w = bf2f(u.s[3]);
        f1.x = bf2f(u.s[4]); f1.y = bf2f(u.s[5]); f1.z = bf2f(u.s[6]); f1.w = bf2f(u.s[7]);
        *(float4*)&vs[h * PAD + d] = f0; *(float4*)&vs[h * PAD + d + 4] = f1;
    }
    __syncthreads();

    {
        int h = tid >> 4, p = tid & 15;
        float sq = 0.f, sk = 0.f;
        #pragma unroll
        for (int j = 0; j < 8; ++j) {
            float x = qs[h * PAD + p + 16 * j]; sq += x * x;
            float y = ks[h * PAD + p + 16 * j]; sk += y * y;
        }
        #pragma unroll
        for (int m = 1; m < 16; m <<= 1) {
            sq += __shfl_xor(sq, m);
            sk += __shfl_xor(sk, m);
        }
        if (p == 0) { rq[h] = rsqrtf(sq); rk[h] = rsqrtf(sk); }
    }
    __syncthreads();

    {
        int h = tid >> 4, g = tid & 15;
        float dot = 0.f;
        #pragma unroll
        for (int d = 0; d < HD; d += 4) {
            float4 q4 = *(const float4*)&qs[h * PAD + d];
            float4 k4 = *(const float4*)&ks[g * PAD + d];
            dot += q4.x * k4.x + q4.y * k4.y + q4.z * k4.z + q4.w * k4.w;
        }
        sm[h * 17 + g] = dot * rq[h] * rk[g] * (1.0f / 128.0f);
    }
    __syncthreads();

    {
        int h = tid & 15, u = tid >> 4;
        float o[8] = {};
        #pragma unroll
        for (int g = 0; g < 16; ++g) {
            float s = sm[h * 17 + g];
            #pragma unroll
            for (int i = 0; i < 8; ++i)
                o[i] = fmaf(s, vs[g * PAD + u + 16 * i], o[i]);
        }
        #pragma unroll
        for (int i = 0; i < 8; ++i)
            ot[(size_t)b * DDIM + u * 16 + 256 * i + h] = f2bf(o[i]);
    }
}

// ---------- in-place row LayerNorm ----------
__global__ __launch_bounds__(256)
void lnorm(float* __restrict__ x, const float* __restrict__ gamma, const float* __restrict__ beta)
{
    const int row = blockIdx.x;
    const int tid = threadIdx.x;
    float* xr = x + (size_t)row * DDIM;

    float4 v0 = *(const float4*)(xr + tid * 4);
    float4 v1 = *(const float4*)(xr + 1024 + tid * 4);
    float s  = v0.x + v0.y + v0.z + v0.w + v1.x + v1.y + v1.z + v1.w;
    float s2 = v0.x*v0.x + v0.y*v0.y + v0.z*v0.z + v0.w*v0.w
             + v1.x*v1.x + v1.y*v1.y + v1.z*v1.z + v1.w*v1.w;

    #pragma unroll
    for (int m = 1; m < 64; m <<= 1) {
        s  += __shfl_xor(s, m);
        s2 += __shfl_xor(s2, m);
    }
    __shared__ float ws1[4], ws2[4];
    if ((tid & 63) == 0) { ws1[tid >> 6] = s; ws2[tid >> 6] = s2; }
    __syncthreads();
    s  = ws1[0] + ws1[1] + ws1[2] + ws1[3];
    s2 = ws2[0] + ws2[1] + ws2[2] + ws2[3];

    const float mu  = s * (1.0f / DDIM);
    const float var = s2 * (1.0f / DDIM) - mu * mu;
    const float rstd = rsqrtf(var + 1e-5f);

    float4 g0 = *(const float4*)(gamma + tid * 4);
    float4 g1 = *(const float4*)(gamma + 1024 + tid * 4);
    float4 b0 = *(const float4*)(beta + tid * 4);
    float4 b1 = *(const float4*)(beta + 1024 + tid * 4);

    v0.x = (v0.x - mu) * rstd * g0.x + b0.x;
    v0.y = (v0.y - mu) * rstd * g0.y + b0.y;
    v0.z = (v0.z - mu) * rstd * g0.z + b0.z;
    v0.w = (v0.w - mu) * rstd * g0.w + b0.w;
    v1.x = (v1.x - mu) * rstd * g1.x + b1.x;
    v1.y = (v1.y - mu) * rstd * g1.y + b1.y;
    v1.z = (v1.z - mu) * rstd * g1.z + b1.z;
    v1.w = (v1.w - mu) * rstd * g1.w + b1.w;

    *(float4*)(xr + tid * 4) = v0;
    *(float4*)(xr + 1024 + tid * 4) = v1;
}

// ---------- launch ----------
extern "C" void kernel_launch(void* const* d_in, const int* in_sizes, int n_in,
                              void* d_out, int out_size, void* d_ws, size_t ws_size,
                              hipStream_t stream)
{
    const float* q     = (const float*)d_in[0];
    const float* k     = (const float*)d_in[1];
    const float* v     = (const float*)d_in[2];
    const float* Wq    = (const float*)d_in[3];
    const float* bq    = (const float*)d_in[4];
    const float* Wk    = (const float*)d_in[5];
    const float* bk    = (const float*)d_in[6];
    const float* Wv    = (const float*)d_in[7];
    const float* bv    = (const float*)d_in[8];
    const float* Wo    = (const float*)d_in[9];
    const float* bo    = (const float*)d_in[10];
    const float* gamma = (const float*)d_in[11];
    const float* beta  = (const float*)d_in[12];

    const size_t BD = (size_t)BDIM * DDIM;
    char* ws = (char*)d_ws;
    size_t off = 0;
    auto alloc = [&](size_t bytes) { void* p = ws + off; off += (bytes + 255) & ~(size_t)255; return p; };

    short* Wqt = (short*)alloc((size_t)DDIM * DDIM * 2);
    short* Wkt = (short*)alloc((size_t)DDIM * DDIM * 2);
    short* Wvt = (short*)alloc((size_t)DDIM * DDIM * 2);
    short* Wot = (short*)alloc((size_t)DDIM * DDIM * 2);
    short* xb  = (short*)alloc(BD * 2);   // bf16 conv buffer (q/k/v in turn), then attn out
    short* qpb = (short*)alloc(BD * 2);   // bf16 q-projection (attn input + residual)
    short* kpb = (short*)alloc(BD * 2);
    short* vpb = (short*)alloc(BD * 2);
    float* xout = (float*)d_out;

    wtrans<<<dim3(DDIM / 32, DDIM / 32, 4), dim3(32, 8), 0, stream>>>(Wq, Wk, Wv, Wo, Wqt, Wkt, Wvt, Wot);

    const int grid = (BDIM / 256) * (DDIM / 256);   // 1024
    const int n8 = (int)(BD / 8);

    cvt1<<<4096, 256, 0, stream>>>(q, xb, n8);
    gemm8<0><<<grid, 512, 0, stream>>>(xb, Wqt, bq, nullptr, qpb, nullptr);
    cvt1<<<4096, 256, 0, stream>>>(k, xb, n8);
    gemm8<0><<<grid, 512, 0, stream>>>(xb, Wkt, bk, nullptr, kpb, nullptr);
    cvt1<<<4096, 256, 0, stream>>>(v, xb, n8);
    gemm8<0><<<grid, 512, 0, stream>>>(xb, Wvt, bv, nullptr, vpb, nullptr);

    attn<<<BDIM, 256, 0, stream>>>(qpb, kpb, vpb, xb);

    gemm8<1><<<grid, 512, 0, stream>>>(xb, Wot, bo, qpb, nullptr, xout);

    lnorm<<<BDIM, 256, 0, stream>>>(xout, gamma, beta);
}

// Round 8
// 1482.133 us; speedup vs baseline: 1.0256x; 1.0256x over previous
//
#include <hip/hip_runtime.h>

typedef __attribute__((ext_vector_type(8))) short bf16x8;
typedef __attribute__((ext_vector_type(4))) float f32x4;

#define BDIM 32768
#define DDIM 2048
#define HNUM 16
#define HD   128

// ---------- helpers ----------
__device__ inline short f2bf(float f) {
    union { float f; unsigned u; } v; v.f = f;
    unsigned r = v.u + 0x7FFFu + ((v.u >> 16) & 1u);   // round-to-nearest-even
    return (short)(r >> 16);
}
__device__ inline float bf2f(short s) {
    union { unsigned u; float f; } v; v.u = ((unsigned)(unsigned short)s) << 16; return v.f;
}

__device__ inline void load_lds16(const void* g, void* l) {
    __builtin_amdgcn_global_load_lds(
        (const __attribute__((address_space(1))) void*)g,
        (__attribute__((address_space(3))) void*)l, 16, 0, 0);
}

#define VMCNT(n) asm volatile("s_waitcnt vmcnt(" #n ")" ::: "memory")
#define BARX     do { __builtin_amdgcn_s_barrier(); __builtin_amdgcn_sched_barrier(0); } while (0)
#define SP1      __builtin_amdgcn_s_setprio(1)
#define SP0      __builtin_amdgcn_s_setprio(0)

// ---------- fp32 -> bf16 convert ----------
__global__ __launch_bounds__(256)
void cvt1(const float* __restrict__ in, short* __restrict__ out, int n8)
{
    int idx = blockIdx.x * 256 + threadIdx.x;
    int stride = gridDim.x * 256;
    for (int ch = idx; ch < n8; ch += stride) {
        const float4* p = (const float4*)(in + (size_t)ch * 8);
        float4 x0 = p[0], x1 = p[1];
        union { bf16x8 v; short s[8]; } o;
        o.s[0] = f2bf(x0.x); o.s[1] = f2bf(x0.y); o.s[2] = f2bf(x0.z); o.s[3] = f2bf(x0.w);
        o.s[4] = f2bf(x1.x); o.s[5] = f2bf(x1.y); o.s[6] = f2bf(x1.z); o.s[7] = f2bf(x1.w);
        *(bf16x8*)(out + (size_t)ch * 8) = o.v;
    }
}

// ---------- weight transpose + convert: W[K][N] fp32 -> Wt[N][K] bf16 ----------
__global__ __launch_bounds__(256)
void wtrans(const float* __restrict__ w0, const float* __restrict__ w1,
            const float* __restrict__ w2, const float* __restrict__ w3,
            short* __restrict__ o0, short* __restrict__ o1,
            short* __restrict__ o2, short* __restrict__ o3)
{
    const float* W = blockIdx.z == 0 ? w0 : blockIdx.z == 1 ? w1 : blockIdx.z == 2 ? w2 : w3;
    short*       O = blockIdx.z == 0 ? o0 : blockIdx.z == 1 ? o1 : blockIdx.z == 2 ? o2 : o3;
    __shared__ float t[32][33];
    int bx = blockIdx.x * 32;   // n
    int by = blockIdx.y * 32;   // k
    int tx = threadIdx.x, ty = threadIdx.y;  // 32 x 8
    #pragma unroll
    for (int r = 0; r < 4; ++r)
        t[ty + 8*r][tx] = W[(size_t)(by + ty + 8*r) * DDIM + bx + tx];
    __syncthreads();
    #pragma unroll
    for (int r = 0; r < 4; ++r)
        O[(size_t)(bx + ty + 8*r) * DDIM + by + tx] = f2bf(t[tx][ty + 8*r]);
}

// ---------- 256x256 8-wave 8-phase bf16 GEMM, r6 skeleton + read-prefetch ----------
// One barrier per phase (loose sync wins: r5/r7=330us tight vs r6=291us loose).
// Fragment reads pipelined one phase ahead WITHIN the current K-tile:
//   ph0: read{A0,B0}, MFMA(0,0), prefetch B1      (12+4 reads)
//   ph1: MFMA(0,1) on held a+b1, prefetch A1->a2  (8 reads)
//   ph2: MFMA(1,0) on a2+b0                       (0 reads)
//   ph3: MFMA(1,1) on a2+b1                       (0 reads)
// Cross-buffer prefetch is NOT done (vmcnt is per-wave; switch needs vmcnt+BAR).
// MFMA operands swapped: acc = mfma(b,a) = C^T fragment -> 8B packed stores.

template<int MH, int NH>
__device__ inline void quadf(f32x4 (&acc)[8][4], bf16x8 (&a)[4][2], bf16x8 (&b)[2][2])
{
    #pragma unroll
    for (int kk = 0; kk < 2; ++kk)
        #pragma unroll
        for (int mi = 0; mi < 4; ++mi)
            #pragma unroll
            for (int ni = 0; ni < 2; ++ni)
                acc[MH*4 + mi][NH*2 + ni] = __builtin_amdgcn_mfma_f32_16x16x32_bf16(
                    b[ni][kk], a[mi][kk], acc[MH*4 + mi][NH*2 + ni], 0, 0, 0);
}

template<int MODE>
__global__ __launch_bounds__(512, 2)
void gemm8(const short* __restrict__ A, const short* __restrict__ Bt,
           const float* __restrict__ bias, const short* __restrict__ resid,
           short* __restrict__ Cb, float* __restrict__ Cf)
{
    constexpr int K = 2048, N = 2048;
    constexpr int NT = K >> 6;            // 32 K-tiles
    constexpr int NP = (NT >> 1) - 1;     // 15 full iterations
    __shared__ __align__(16) short lds[2][2][256 * 64];
    const int tid = threadIdx.x;

    constexpr int cpx = 128;              // 1024 wgs / 8 XCDs
    const int wg  = ((int)blockIdx.x & 7) * cpx + ((int)blockIdx.x >> 3);
    const int tm  = wg >> 3, tn = wg & 7;

    const int wave = tid >> 6, lane = tid & 63;
    const int wm = wave >> 2, wn = wave & 3;        // 2 x 4 wave grid, 128x64 out each
    const int lrow = lane & 15, lgrp = lane >> 4;

    const short* Ab = A  + (size_t)tm * 256 * K;
    const short* Bb = Bt + (size_t)tn * 256 * K;

    // ---- staging streams: precomputed pointers + LDS offsets ----
    const int r0 = tid >> 3, c0 = tid & 7;
    const int cg = c0 ^ (r0 & 7);                   // inverse swizzle on source
    constexpr size_t DL  = (size_t)128 * K;         // second-load global delta
    constexpr int    DLD = 128 * 64;                // second-load LDS delta
    const int rB = ((r0 >> 5) << 6) | (r0 & 31);    // B row for B0 stream

    const short* pA0 = Ab + (size_t)r0 * K + cg * 8;
    const short* pA1 = Ab + (size_t)(64 + r0) * K + cg * 8;
    const short* pB0 = Bb + (size_t)rB * K + cg * 8;
    const short* pB1 = Bb + (size_t)(rB + 32) * K + cg * 8;

    short* base = &lds[0][0][0];
    int oA0 = r0 * 64 + c0 * 8;                     // into [buf][0]
    int oA1 = (64 + r0) * 64 + c0 * 8;
    int oB0 = 16384 + rB * 64 + c0 * 8;             // into [buf][1]
    int oB1 = 16384 + (rB + 32) * 64 + c0 * 8;

    auto stA0 = [&]{ load_lds16(pA0, base + oA0); load_lds16(pA0 + DL, base + oA0 + DLD); pA0 += 64; oA0 ^= 32768; };
    auto stA1 = [&]{ load_lds16(pA1, base + oA1); load_lds16(pA1 + DL, base + oA1 + DLD); pA1 += 64; oA1 ^= 32768; };
    auto stB0 = [&]{ load_lds16(pB0, base + oB0); load_lds16(pB0 + DL, base + oB0 + DLD); pB0 += 64; oB0 ^= 32768; };
    auto stB1 = [&]{ load_lds16(pB1, base + oB1); load_lds16(pB1 + DL, base + oB1 + DLD); pB1 += 64; oB1 ^= 32768; };

    // ---- fragment reads (compiler inserts counted lgkmcnt before MFMA uses) ----
    bf16x8 a[4][2], a2[4][2], b0[2][2], b1[2][2];
    const int sw0 = (lgrp ^ (lrow & 7)) * 8;
    const int sw1 = ((4 + lgrp) ^ (lrow & 7)) * 8;

    auto readA = [&](int buf, int mh, bf16x8 (&dst)[4][2]) {
        const short* s = &lds[buf][0][0];
        int bb = (wm * 128 + mh * 64 + lrow) * 64;
        #pragma unroll
        for (int mi = 0; mi < 4; ++mi) {
            dst[mi][0] = *(const bf16x8*)&s[bb + mi * 1024 + sw0];
            dst[mi][1] = *(const bf16x8*)&s[bb + mi * 1024 + sw1];
        }
    };
    auto readB = [&](int buf, int nh, bf16x8 (&b)[2][2]) {
        const short* s = &lds[buf][1][0];
        int bb = (wn * 64 + nh * 32 + lrow) * 64;
        #pragma unroll
        for (int ni = 0; ni < 2; ++ni) {
            b[ni][0] = *(const bf16x8*)&s[bb + ni * 1024 + sw0];
            b[ni][1] = *(const bf16x8*)&s[bb + ni * 1024 + sw1];
        }
    };

    f32x4 acc[8][4] = {};

    // prologue: tile0 -> buf0 (full), tile1 -> buf1 (A0,B0,B1); 14 loads in flight
    stA0(); stB0(); stB1(); stA1();
    stA0(); stB0(); stB1();

    for (int j = 0; j < NP; ++j) {
        // ph0 (buf0 = tile 2j): vmcnt(6) lands tile 2j
        VMCNT(6); BARX;
        stA1();                              // A1(2j+1) -> buf1
        readA(0, 0, a); readB(0, 0, b0);
        SP1; quadf<0,0>(acc, a, b0); SP0;
        readB(0, 1, b1);                     // prefetch for ph1
        // ph1
        BARX;
        stA0();                              // A0(2j+2) -> buf0
        SP1; quadf<0,1>(acc, a, b1); SP0;
        readA(0, 1, a2);                     // prefetch for ph2/ph3
        // ph2 (no reads)
        BARX;
        stB0();                              // B0(2j+2) -> buf0
        SP1; quadf<1,0>(acc, a2, b0); SP0;
        // ph3 (no reads)
        BARX;
        stB1();                              // B1(2j+2) -> buf0
        SP1; quadf<1,1>(acc, a2, b1); SP0;
        // ph4 (buf1 = tile 2j+1): vmcnt(6) lands tile 2j+1
        VMCNT(6); BARX;
        stA1();                              // A1(2j+2) -> buf0
        readA(1, 0, a); readB(1, 0, b0);
        SP1; quadf<0,0>(acc, a, b0); SP0;
        readB(1, 1, b1);
        // ph5
        BARX;
        stA0();                              // A0(2j+3) -> buf1
        SP1; quadf<0,1>(acc, a, b1); SP0;
        readA(1, 1, a2);
        // ph6
        BARX;
        stB0();                              // B0(2j+3) -> buf1
        SP1; quadf<1,0>(acc, a2, b0); SP0;
        // ph7
        BARX;
        stB1();                              // B1(2j+3) -> buf1
        SP1; quadf<1,1>(acc, a2, b1); SP0;
    }

    // epilogue: buf0 = tile NT-2, buf1 = tile NT-1; only A1(NT-1) left to stage
    VMCNT(6); BARX;
    stA1();                                  // A1(NT-1) -> buf1
    readA(0, 0, a); readB(0, 0, b0);
    SP1; quadf<0,0>(acc, a, b0); SP0;
    readB(0, 1, b1);
    quadf<0,1>(acc, a, b1);
    readA(0, 1, a);
    quadf<1,0>(acc, a, b0);
    quadf<1,1>(acc, a, b1);
    VMCNT(0); BARX;                          // tile NT-1 fully landed
    readA(1, 0, a); readB(1, 0, b0);
    quadf<0,0>(acc, a, b0);
    readB(1, 1, b1);
    quadf<0,1>(acc, a, b1);
    readA(1, 1, a);
    quadf<1,0>(acc, a, b0);
    quadf<1,1>(acc, a, b1);

    // ---- C write (C^T fragments): lane owns row=lrow, 4 consecutive cols ----
    #pragma unroll
    for (int m = 0; m < 8; ++m) {
        const int row = tm * 256 + wm * 128 + m * 16 + lrow;
        const size_t rb = (size_t)row * N;
        #pragma unroll
        for (int n = 0; n < 4; ++n) {
            const int col = tn * 256 + wn * 64 + n * 16 + lgrp * 4;
            f32x4 v = acc[m][n];
            float4 bv = *(const float4*)&bias[col];
            v[0] += bv.x; v[1] += bv.y; v[2] += bv.z; v[3] += bv.w;
            if (MODE == 0) {
                uint2 w;
                w.x = (unsigned)(unsigned short)f2bf(v[0]) | ((unsigned)(unsigned short)f2bf(v[1]) << 16);
                w.y = (unsigned)(unsigned short)f2bf(v[2]) | ((unsigned)(unsigned short)f2bf(v[3]) << 16);
                *(uint2*)(Cb + rb + col) = w;
            } else {
                uint2 rv = *(const uint2*)(resid + rb + col);
                v[0] += bf2f((short)(rv.x & 0xffff));
                v[1] += bf2f((short)(rv.x >> 16));
                v[2] += bf2f((short)(rv.y & 0xffff));
                v[3] += bf2f((short)(rv.y >> 16));
                *(f32x4*)(Cf + rb + col) = v;
            }
        }
    }
}

// ---------- per-sample 16-head cosine attention (bf16 in), transposed bf16 out ----------
#define PAD 132

__global__ __launch_bounds__(256)
void attn(const short* __restrict__ qp, const short* __restrict__ kp,
          const short* __restrict__ vp, short* __restrict__ ot)
{
    __shared__ __align__(16) float qs[HNUM * PAD];
    __shared__ __align__(16) float ks[HNUM * PAD];
    __shared__ __align__(16) float vs[HNUM * PAD];
    __shared__ float rq[HNUM], rk[HNUM], sm[HNUM * 17];

    const int b = blockIdx.x;
    const int tid = threadIdx.x;
    const short* qr = qp + (size_t)b * DDIM;
    const short* kr = kp + (size_t)b * DDIM;
    const short* vr = vp + (size_t)b * DDIM;

    {
        int e = tid * 8;
        int h = e >> 7, d = e & 127;
        union { bf16x8 v; short s[8]; } u;
        float4 f0, f1;
        u.v = *(const bf16x8*)(qr + e);
        f0.x = bf2f(u.s[0]); f0.y = bf2f(u.s[1]); f0.z = bf2f(u.s[2]); f0.w = bf2f(u.s[3]);
        f1.x = bf2f(u.s[4]); f1.y = bf2f(u.s[5]); f1.z = bf2f(u.s[6]); f1.w = bf2f(u.s[7]);
        *(float4*)&qs[h * PAD + d] = f0; *(float4*)&qs[h * PAD + d + 4] = f1;
        u.v = *(const bf16x8*)(kr + e);
        f0.x = bf2f(u.s[0]); f0.y = bf2f(u.s[1]); f0.z = bf2f(u.s[2]); f0.w = bf2f(u.s[3]);
        f1.x = bf2f(u.s[4]); f1.y = bf2f(u.s[5]); f1.z = bf2f(u.s[6]); f1.w = bf2f(u.s[7]);
        *(float4*)&ks[h * PAD + d] = f0; *(float4*)&ks[h * PAD + d + 4] = f1;
        u.v = *(const bf16x8*)(vr + e);
        f0.x = bf2f(u.s[0]); f0.y = bf2f(u.s[1]); f0.z = bf2f(u.s[2]); f0.w = bf2f(u.s[3]);
        f1.x = bf2f(u.s[4]); f1.y = bf2f(u.s[5]); f1.z = bf2f(u.s[6]); f1.w = bf2f(u.s[7]);
        *(float4*)&vs[h * PAD + d] = f0; *(float4*)&vs[h * PAD + d + 4] = f1;
    }
    __syncthreads();

    {
        int h = tid >> 4, p = tid & 15;
        float sq = 0.f, sk = 0.f;
        #pragma unroll
        for (int j = 0; j < 8; ++j) {
            float x = qs[h * PAD + p + 16 * j]; sq += x * x;
            float y = ks[h * PAD + p + 16 * j]; sk += y * y;
        }
        #pragma unroll
        for (int m = 1; m < 16; m <<= 1) {
            sq += __shfl_xor(sq, m);
            sk += __shfl_xor(sk, m);
        }
        if (p == 0) { rq[h] = rsqrtf(sq); rk[h] = rsqrtf(sk); }
    }
    __syncthreads();

    {
        int h = tid >> 4, g = tid & 15;
        float dot = 0.f;
        #pragma unroll
        for (int d = 0; d < HD; d += 4) {
            float4 q4 = *(const float4*)&qs[h * PAD + d];
            float4 k4 = *(const float4*)&ks[g * PAD + d];
            dot += q4.x * k4.x + q4.y * k4.y + q4.z * k4.z + q4.w * k4.w;
        }
        sm[h * 17 + g] = dot * rq[h] * rk[g] * (1.0f / 128.0f);
    }
    __syncthreads();

    {
        int h = tid & 15, u = tid >> 4;
        float o[8] = {};
        #pragma unroll
        for (int g = 0; g < 16; ++g) {
            float s = sm[h * 17 + g];
            #pragma unroll
            for (int i = 0; i < 8; ++i)
                o[i] = fmaf(s, vs[g * PAD + u + 16 * i], o[i]);
        }
        #pragma unroll
        for (int i = 0; i < 8; ++i)
            ot[(size_t)b * DDIM + u * 16 + 256 * i + h] = f2bf(o[i]);
    }
}

// ---------- in-place row LayerNorm ----------
__global__ __launch_bounds__(256)
void lnorm(float* __restrict__ x, const float* __restrict__ gamma, const float* __restrict__ beta)
{
    const int row = blockIdx.x;
    const int tid = threadIdx.x;
    float* xr = x + (size_t)row * DDIM;

    float4 v0 = *(const float4*)(xr + tid * 4);
    float4 v1 = *(const float4*)(xr + 1024 + tid * 4);
    float s  = v0.x + v0.y + v0.z + v0.w + v1.x + v1.y + v1.z + v1.w;
    float s2 = v0.x*v0.x + v0.y*v0.y + v0.z*v0.z + v0.w*v0.w
             + v1.x*v1.x + v1.y*v1.y + v1.z*v1.z + v1.w*v1.w;

    #pragma unroll
    for (int m = 1; m < 64; m <<= 1) {
        s  += __shfl_xor(s, m);
        s2 += __shfl_xor(s2, m);
    }
    __shared__ float ws1[4], ws2[4];
    if ((tid & 63) == 0) { ws1[tid >> 6] = s; ws2[tid >> 6] = s2; }
    __syncthreads();
    s  = ws1[0] + ws1[1] + ws1[2] + ws1[3];
    s2 = ws2[0] + ws2[1] + ws2[2] + ws2[3];

    const float mu  = s * (1.0f / DDIM);
    const float var = s2 * (1.0f / DDIM) - mu * mu;
    const float rstd = rsqrtf(var + 1e-5f);

    float4 g0 = *(const float4*)(gamma + tid * 4);
    float4 g1 = *(const float4*)(gamma + 1024 + tid * 4);
    float4 b0 = *(const float4*)(beta + tid * 4);
    float4 b1 = *(const float4*)(beta + 1024 + tid * 4);

    v0.x = (v0.x - mu) * rstd * g0.x + b0.x;
    v0.y = (v0.y - mu) * rstd * g0.y + b0.y;
    v0.z = (v0.z - mu) * rstd * g0.z + b0.z;
    v0.w = (v0.w - mu) * rstd * g0.w + b0.w;
    v1.x = (v1.x - mu) * rstd * g1.x + b1.x;
    v1.y = (v1.y - mu) * rstd * g1.y + b1.y;
    v1.z = (v1.z - mu) * rstd * g1.z + b1.z;
    v1.w = (v1.w - mu) * rstd * g1.w + b1.w;

    *(float4*)(xr + tid * 4) = v0;
    *(float4*)(xr + 1024 + tid * 4) = v1;
}

// ---------- launch ----------
extern "C" void kernel_launch(void* const* d_in, const int* in_sizes, int n_in,
                              void* d_out, int out_size, void* d_ws, size_t ws_size,
                              hipStream_t stream)
{
    const float* q     = (const float*)d_in[0];
    const float* k     = (const float*)d_in[1];
    const float* v     = (const float*)d_in[2];
    const float* Wq    = (const float*)d_in[3];
    const float* bq    = (const float*)d_in[4];
    const float* Wk    = (const float*)d_in[5];
    const float* bk    = (const float*)d_in[6];
    const float* Wv    = (const float*)d_in[7];
    const float* bv    = (const float*)d_in[8];
    const float* Wo    = (const float*)d_in[9];
    const float* bo    = (const float*)d_in[10];
    const float* gamma = (const float*)d_in[11];
    const float* beta  = (const float*)d_in[12];

    const size_t BD = (size_t)BDIM * DDIM;
    char* ws = (char*)d_ws;
    size_t off = 0;
    auto alloc = [&](size_t bytes) { void* p = ws + off; off += (bytes + 255) & ~(size_t)255; return p; };

    short* Wqt = (short*)alloc((size_t)DDIM * DDIM * 2);
    short* Wkt = (short*)alloc((size_t)DDIM * DDIM * 2);
    short* Wvt = (short*)alloc((size_t)DDIM * DDIM * 2);
    short* Wot = (short*)alloc((size_t)DDIM * DDIM * 2);
    short* xb  = (short*)alloc(BD * 2);   // bf16 conv buffer (q/k/v in turn), then attn out
    short* qpb = (short*)alloc(BD * 2);   // bf16 q-projection (attn input + residual)
    short* kpb = (short*)alloc(BD * 2);
    short* vpb = (short*)alloc(BD * 2);
    float* xout = (float*)d_out;

    wtrans<<<dim3(DDIM / 32, DDIM / 32, 4), dim3(32, 8), 0, stream>>>(Wq, Wk, Wv, Wo, Wqt, Wkt, Wvt, Wot);

    const int grid = (BDIM / 256) * (DDIM / 256);   // 1024
    const int n8 = (int)(BD / 8);

    cvt1<<<4096, 256, 0, stream>>>(q, xb, n8);
    gemm8<0><<<grid, 512, 0, stream>>>(xb, Wqt, bq, nullptr, qpb, nullptr);
    cvt1<<<4096, 256, 0, stream>>>(k, xb, n8);
    gemm8<0><<<grid, 512, 0, stream>>>(xb, Wkt, bk, nullptr, kpb, nullptr);
    cvt1<<<4096, 256, 0, stream>>>(v, xb, n8);
    gemm8<0><<<grid, 512, 0, stream>>>(xb, Wvt, bv, nullptr, vpb, nullptr);

    attn<<<BDIM, 256, 0, stream>>>(qpb, kpb, vpb, xb);

    gemm8<1><<<grid, 512, 0, stream>>>(xb, Wot, bo, qpb, nullptr, xout);

    lnorm<<<BDIM, 256, 0, stream>>>(xout, gamma, beta);
}